// Round 10
// baseline (113.165 us; speedup 1.0000x reference)
//
#include <hip/hip_runtime.h>
#include <hip/hip_fp16.h>
#include <stdint.h>

// DIAGNOSTIC ROUND: attn_kernel is byte-identical to R9 (29.8 us total).
// probe_front = phase-A clone (K stream + dots + scS writes) x8 reps, sized
// to exceed the ~40us harness fills so it appears in the duration-sorted
// top-5 table. Read-out: front-cost ~= P/8; epilogue ~= attn_total - front.
#define TT   1024
#define BB   4
#define NTH  256
#define REP  8
#define NEG_INF (-3.4e38f)
#define QH_U32 (BB * TT * 32)   // Q as half2 words; Kh follows at same size

typedef __fp16 f16x2 __attribute__((ext_vector_type(2)));
union U32H2 { uint32_t u; f16x2 h; };

__device__ __forceinline__ uint32_t rotl32(uint32_t x, int d) {
  return (x << d) | (x >> (32 - d));
}

// JAX partitionable threefry (key(42)) keep decision  [verified R1]
__device__ __forceinline__ bool keep_at(uint32_t i) {
  uint32_t x0 = 0u, x1 = i;
  const uint32_t ks0 = 0u, ks1 = 42u;
  const uint32_t ks2 = 0x1BD11BDAu ^ ks0 ^ ks1;
  x0 += ks0; x1 += ks1;
#define R4(a,b,c,d)                              \
  x0 += x1; x1 = rotl32(x1,(a)); x1 ^= x0;       \
  x0 += x1; x1 = rotl32(x1,(b)); x1 ^= x0;       \
  x0 += x1; x1 = rotl32(x1,(c)); x1 ^= x0;       \
  x0 += x1; x1 = rotl32(x1,(d)); x1 ^= x0;
  R4(13,15,26,6)   x0 += ks1; x1 += ks2 + 1u;
  R4(17,29,16,24)  x0 += ks2; x1 += ks0 + 2u;
  R4(13,15,26,6)   x0 += ks0; x1 += ks1 + 3u;
  R4(17,29,16,24)  x0 += ks1; x1 += ks2 + 4u;
  R4(13,15,26,6)   x0 += ks2; x1 += ks0 + 5u;
#undef R4
  const uint32_t bits = x0 ^ x1;
  const float u = __uint_as_float((bits >> 9) | 0x3f800000u) - 1.0f;
  return u < 0.8f;
}

__device__ __forceinline__ uint32_t pack2(float x, float y) {
  U32H2 t; t.h = __builtin_amdgcn_cvt_pkrtz(x, y);
  return t.u;
}

__device__ __forceinline__ f16x2 as_h2(uint32_t u) {
  U32H2 t; t.u = u; return t.h;
}

#if __has_builtin(__builtin_amdgcn_fdot2)
__device__ __forceinline__ float dot2acc(float a, uint32_t q, uint32_t k) {
  return __builtin_amdgcn_fdot2(as_h2(q), as_h2(k), a, false);
}
#else
__device__ __forceinline__ float dot2acc(float a, uint32_t q, uint32_t k) {
  const f16x2 qh = as_h2(q), kh = as_h2(k);
  a = fmaf((float)qh[0], (float)kh[0], a);
  return fmaf((float)qh[1], (float)kh[1], a);
}
#endif

__device__ __forceinline__ float dot16B(uint4 q, uint4 k) {
  float a = 0.f;
  a = dot2acc(a, q.x, k.x);
  a = dot2acc(a, q.y, k.y);
  a = dot2acc(a, q.z, k.z);
  a = dot2acc(a, q.w, k.w);
  return a;
}

template <int CTRL>
__device__ __forceinline__ float add_dpp(float x) {
  const int s =
      __builtin_amdgcn_update_dpp(0, __float_as_int(x), CTRL, 0xF, 0xF, true);
  return x + __int_as_float(s);
}

__device__ __forceinline__ float reduce8(float a) {
  a = add_dpp<0xB1>(a);    // lane ^ 1
  a = add_dpp<0x4E>(a);    // lane ^ 2
  a = add_dpp<0x141>(a);   // lane ^ 4 (row_half_mirror)
  return a;
}

// ---- pre-pass: fp32 -> packed f16 for Q and K (1 MB into d_ws) ----
__global__ __launch_bounds__(NTH)
void cvt_kernel(const float* __restrict__ Q, const float* __restrict__ K,
                uint32_t* __restrict__ W) {
  const int i = blockIdx.x * NTH + threadIdx.x;
  const float2 qf = reinterpret_cast<const float2*>(Q)[i];
  W[i] = pack2(qf.x, qf.y);
  const float2 kf = reinterpret_cast<const float2*>(K)[i];
  W[QH_U32 + i] = pack2(kf.x, kf.y);
}

// ---- DIAGNOSTIC: phase-A x REP. Opaque 'off' defeats load hoisting;
// per-rep checksum over scS defeats DCE of dots and LDS writes. ----
__global__ __launch_bounds__(NTH)
void probe_front(const uint32_t* __restrict__ W, float* __restrict__ PW) {
  __shared__ float scS[4][TT];
  const int tid = threadIdx.x;
  const int wv  = tid >> 6, ln = tid & 63;
  const int o   = ln & 7;
  const int rg  = ln >> 3;
  const int g   = blockIdx.x & 255;
  const int b   = blockIdx.x >> 8;
  int rowA[4];
  rowA[0] = 2 * g; rowA[1] = 2 * g + 1;
  rowA[2] = 1022 - 2 * g; rowA[3] = 1023 - 2 * g;

  float chk = 0.f;
  int off = 0;
  for (int rep = 0; rep < REP; ++rep) {
    asm volatile("" : "+s"(off));            // opaque 0: blocks hoisting
    float* scFlat = &scS[0][0];
#pragma unroll
    for (int t = 0; t < 16; ++t) scFlat[tid + NTH * t] = NEG_INF;
    const uint4* Qh4 = reinterpret_cast<const uint4*>(W + off) + (size_t)b * TT * 8;
    const uint4* K4  = reinterpret_cast<const uint4*>(W + off + QH_U32) + (size_t)b * TT * 8;
    uint4 qw[4];
#pragma unroll
    for (int t = 0; t < 4; ++t) qw[t] = Qh4[(size_t)rowA[t] * 8 + o];
    __syncthreads();

    const int nC = (rowA[3] - 8 * wv) / 32 + 1;
    int jb = 8 * wv;
    uint4 kw = K4[(size_t)jb * 8 + ln];
    for (int c = 0; c < nC; ++c) {
      const int jbn = (c + 1 < nC) ? (jb + 32) : jb;
      const uint4 kwN = K4[(size_t)jbn * 8 + ln];
      const int row = jb + rg;
#pragma unroll
      for (int t = 0; t < 4; ++t) {
        if (jb <= rowA[t]) {
          const float a = reduce8(dot16B(qw[t], kw));
          if (o == 0 && row <= rowA[t]) scS[t][row] = a * 0.125f;
        }
      }
      kw = kwN;
      jb += 32;
    }
    __syncthreads();
#pragma unroll
    for (int t = 0; t < 4; ++t)
#pragma unroll
      for (int i = 0; i < 4; ++i) chk += scS[t][tid + 256 * i];
    __syncthreads();
  }
  PW[blockIdx.x * NTH + tid] = chk;          // keep everything live
}

// ---- REAL kernel: byte-identical structure to R9 ----
__global__ __launch_bounds__(NTH)
void attn_kernel(const uint32_t* __restrict__ W, float* __restrict__ O) {
  __shared__ float scS[4][TT];
  __shared__ float redM[4][4], redS[4][4];

  const int tid = threadIdx.x;
  const int wv  = tid >> 6, ln = tid & 63;
  const int o   = ln & 7;
  const int rg  = ln >> 3;
  const int g   = blockIdx.x & 255;
  const int b   = blockIdx.x >> 8;
  int rowA[4];
  rowA[0] = 2 * g; rowA[1] = 2 * g + 1;
  rowA[2] = 1022 - 2 * g; rowA[3] = 1023 - 2 * g;

  float* scFlat = &scS[0][0];
#pragma unroll
  for (int t = 0; t < 16; ++t) scFlat[tid + NTH * t] = NEG_INF;

  const uint4* Qh4 = reinterpret_cast<const uint4*>(W) + (size_t)b * TT * 8;
  const uint4* K4  = reinterpret_cast<const uint4*>(W + QH_U32) + (size_t)b * TT * 8;
  uint4 qw[4];
#pragma unroll
  for (int t = 0; t < 4; ++t) qw[t] = Qh4[(size_t)rowA[t] * 8 + o];

  __syncthreads();

  const int nC = (rowA[3] - 8 * wv) / 32 + 1;
  int jb = 8 * wv;
  uint4 kw = K4[(size_t)jb * 8 + ln];
  for (int c = 0; c < nC; ++c) {
    const int jbn = (c + 1 < nC) ? (jb + 32) : jb;
    const uint4 kwN = K4[(size_t)jbn * 8 + ln];
    const int row = jb + rg;
#pragma unroll
    for (int t = 0; t < 4; ++t) {
      if (jb <= rowA[t]) {
        const float a = reduce8(dot16B(qw[t], kw));
        if (o == 0 && row <= rowA[t]) scS[t][row] = a * 0.125f;
      }
    }
    kw = kwN;
    jb += 32;
  }
  __syncthreads();

  float e[4][4], pm[4];
#pragma unroll
  for (int r = 0; r < 4; ++r) {
#pragma unroll
    for (int i = 0; i < 4; ++i) e[r][i] = scS[r][tid + 256 * i];
    pm[r] = fmaxf(fmaxf(e[r][0], e[r][1]), fmaxf(e[r][2], e[r][3]));
  }
#pragma unroll
  for (int off = 32; off; off >>= 1)
#pragma unroll
    for (int r = 0; r < 4; ++r) pm[r] = fmaxf(pm[r], __shfl_xor(pm[r], off));
  if (ln == 0) {
#pragma unroll
    for (int r = 0; r < 4; ++r) redM[r][wv] = pm[r];
  }
  __syncthreads();
  float m[4], ps[4];
#pragma unroll
  for (int r = 0; r < 4; ++r) {
    m[r] = fmaxf(fmaxf(redM[r][0], redM[r][1]), fmaxf(redM[r][2], redM[r][3]));
    float s0 = 0.f;
#pragma unroll
    for (int i = 0; i < 4; ++i) {
      const float ev = __expf(e[r][i] - m[r]);
      e[r][i] = ev;
      s0 += ev;
    }
    ps[r] = s0;
  }
#pragma unroll
  for (int off = 32; off; off >>= 1)
#pragma unroll
    for (int r = 0; r < 4; ++r) ps[r] += __shfl_xor(ps[r], off);
  if (ln == 0) {
#pragma unroll
    for (int r = 0; r < 4; ++r) redS[r][wv] = ps[r];
  }
  __syncthreads();
  float rs[4];
#pragma unroll
  for (int r = 0; r < 4; ++r)
    rs[r] = 1.25f / (redS[r][0] + redS[r][1] + redS[r][2] + redS[r][3]);

#pragma unroll
  for (int r = 0; r < 4; ++r) {
    const int row = rowA[r];
    const float scv = rs[r];
    const size_t base = ((size_t)b * TT + row) * TT;
#pragma unroll
    for (int i = 0; i < 4; ++i) {
      const int j = tid + 256 * i;
      float v = 0.f;
      if (j <= row)
        v = keep_at((uint32_t)(base + j)) ? e[r][i] * scv : 0.f;
      O[base + j] = v;
    }
  }
}

extern "C" void kernel_launch(void* const* d_in, const int* in_sizes, int n_in,
                              void* d_out, int out_size, void* d_ws, size_t ws_size,
                              hipStream_t stream) {
  const float* q = (const float*)d_in[0];
  const float* k = (const float*)d_in[1];
  float* out = (float*)d_out;
  uint32_t* w = (uint32_t*)d_ws;               // 1 MB f16 staging
  float* probeOut = (float*)(w + 2 * QH_U32);  // probe scratch after staging
  cvt_kernel<<<dim3(QH_U32 / NTH), NTH, 0, stream>>>(q, k, w);
  if (ws_size >= (size_t)(2 * QH_U32) * 4 + (size_t)BB * 256 * NTH * 4 + 64)
    probe_front<<<dim3(BB * 256), NTH, 0, stream>>>(w, probeOut);
  attn_kernel<<<dim3(BB * 256), NTH, 0, stream>>>(w, out);
}

// Round 11
// 31.558 us; speedup vs baseline: 3.5859x; 3.5859x over previous
//
#include <hip/hip_runtime.h>
#include <stdint.h>

// B=4, T=1024, D=64 causal attention probs + deterministic JAX dropout.
// MFMA rewrite: cvt packs Q (row-major f16) and K (B-frag-major f16) into d_ws.
// attn: 256 blocks x 512 thr; block owns interleaved 16-row q-tile
// {g+64m} (uniform work, no mirror pairing). Pass1: mfma scores + online
// (m,s) via 16-lane DPP reduces; LDS combine across 8 waves. Pass2: re-mfma,
// P=exp(S-M)*rs, threefry dropout (wave-uniform skip for fully-masked regs).
#define TT 1024
#define BB 4
#define NEG_BIG (-3.4e38f)

typedef __fp16 fp16x2 __attribute__((ext_vector_type(2)));
typedef __fp16 fp16x8 __attribute__((ext_vector_type(8)));
typedef float  floatx4 __attribute__((ext_vector_type(4)));
union U32H2 { uint32_t u; fp16x2 h; };
union U4H8  { uint4 u; fp16x8 h; };

__device__ __forceinline__ uint32_t rotl32(uint32_t x, int d) {
  return (x << d) | (x >> (32 - d));
}

// JAX partitionable threefry (key(42)) keep decision  [verified R1]
__device__ __forceinline__ bool keep_at(uint32_t i) {
  uint32_t x0 = 0u, x1 = i;
  const uint32_t ks0 = 0u, ks1 = 42u;
  const uint32_t ks2 = 0x1BD11BDAu ^ ks0 ^ ks1;
  x0 += ks0; x1 += ks1;
#define R4(a,b,c,d)                              \
  x0 += x1; x1 = rotl32(x1,(a)); x1 ^= x0;       \
  x0 += x1; x1 = rotl32(x1,(b)); x1 ^= x0;       \
  x0 += x1; x1 = rotl32(x1,(c)); x1 ^= x0;       \
  x0 += x1; x1 = rotl32(x1,(d)); x1 ^= x0;
  R4(13,15,26,6)   x0 += ks1; x1 += ks2 + 1u;
  R4(17,29,16,24)  x0 += ks2; x1 += ks0 + 2u;
  R4(13,15,26,6)   x0 += ks0; x1 += ks1 + 3u;
  R4(17,29,16,24)  x0 += ks1; x1 += ks2 + 4u;
  R4(13,15,26,6)   x0 += ks2; x1 += ks0 + 5u;
#undef R4
  const uint32_t bits = x0 ^ x1;
  const float u = __uint_as_float((bits >> 9) | 0x3f800000u) - 1.0f;
  return u < 0.8f;
}

__device__ __forceinline__ uint32_t pack2(float x, float y) {
  U32H2 t; t.h = __builtin_amdgcn_cvt_pkrtz(x, y);
  return t.u;
}

template <int CTRL>
__device__ __forceinline__ float maxdpp(float x) {
  const int s =
      __builtin_amdgcn_update_dpp(0, __float_as_int(x), CTRL, 0xF, 0xF, true);
  return fmaxf(x, __int_as_float(s));
}
template <int CTRL>
__device__ __forceinline__ float adddpp(float x) {
  const int s =
      __builtin_amdgcn_update_dpp(0, __float_as_int(x), CTRL, 0xF, 0xF, true);
  return x + __int_as_float(s);
}
// reduce over the 16 lanes of a (l>>4) group: xor1, xor2, xor4, xor8
__device__ __forceinline__ float rmax16(float a) {
  a = maxdpp<0xB1>(a);  a = maxdpp<0x4E>(a);
  a = maxdpp<0x141>(a); a = maxdpp<0x140>(a);
  return a;
}
__device__ __forceinline__ float radd16(float a) {
  a = adddpp<0xB1>(a);  a = adddpp<0x4E>(a);
  a = adddpp<0x141>(a); a = adddpp<0x140>(a);
  return a;
}

// ---- cvt: Q -> row-major f16 (uint4[32768]); K -> B-frag-major f16 ----
// K frag layout: [b][jt][c][lane] uint4, lane l supplies B[k=c*32+(l>>4)*8+i][col=l&15]
__global__ __launch_bounds__(256)
void cvt_kernel(const float* __restrict__ Q, const float* __restrict__ K,
                uint32_t* __restrict__ W) {
  const int t = blockIdx.x * 256 + threadIdx.x;   // 0..32767
  uint4* W4 = reinterpret_cast<uint4*>(W);
  {
    const int row = t >> 3, c8 = t & 7;           // global row, 8-float chunk
    const float4 f0 = reinterpret_cast<const float4*>(Q)[row * 16 + c8 * 2];
    const float4 f1 = reinterpret_cast<const float4*>(Q)[row * 16 + c8 * 2 + 1];
    uint4 d;
    d.x = pack2(f0.x, f0.y); d.y = pack2(f0.z, f0.w);
    d.z = pack2(f1.x, f1.y); d.w = pack2(f1.z, f1.w);
    W4[t] = d;
  }
  {
    const int l = t & 63, c = (t >> 6) & 1, jt = (t >> 7) & 63, b = t >> 13;
    const int jrow = jt * 16 + (l & 15);
    const int kof  = c * 32 + (l >> 4) * 8;       // first of 8 f16 elems
    const float4 f0 =
        reinterpret_cast<const float4*>(K)[((b << 10) + jrow) * 16 + (kof >> 2)];
    const float4 f1 =
        reinterpret_cast<const float4*>(K)[((b << 10) + jrow) * 16 + (kof >> 2) + 1];
    uint4 d;
    d.x = pack2(f0.x, f0.y); d.y = pack2(f0.z, f0.w);
    d.z = pack2(f1.x, f1.y); d.w = pack2(f1.z, f1.w);
    W4[32768 + t] = d;
  }
}

__global__ __launch_bounds__(512)
void attn_kernel(const uint32_t* __restrict__ W, float* __restrict__ O) {
  __shared__ float redM[16][8], redS[16][8];

  const int tid = threadIdx.x;
  const int wv  = tid >> 6, ln = tid & 63;
  const int g   = blockIdx.x & 63;
  const int b   = blockIdx.x >> 6;

  const uint4* W4 = reinterpret_cast<const uint4*>(W);
  const uint4* Kp = W4 + 32768 + (size_t)b * 8192;

  // A-frags for the q-tile (rows g+64m): lane supplies A[row=l&15][k=(l>>4)*8+i]
  const int arow = g + 64 * (ln & 15);
  U4H8 qa0, qa1;
  qa0.u = W4[((size_t)(b << 10) + arow) * 8 + (ln >> 4)];
  qa1.u = W4[((size_t)(b << 10) + arow) * 8 + 4 + (ln >> 4)];

  // D-side rows per reg r: m=(l>>4)*4+r, global row=g+64m
  int rowD[4]; uint32_t obase[4];
#pragma unroll
  for (int r = 0; r < 4; ++r) {
    const int m = (ln >> 4) * 4 + r;
    rowD[r]  = g + 64 * m;
    obase[r] = ((uint32_t)b << 20) | ((uint32_t)rowD[r] << 10);
  }
  const int colL = ln & 15;

  // ---- pass 1: online (m, s) over the wave's jt stripe ----
  float mReg[4] = {NEG_BIG, NEG_BIG, NEG_BIG, NEG_BIG};
  float sReg[4] = {0.f, 0.f, 0.f, 0.f};
  {
    int jt = wv;
    uint4 c0 = Kp[(size_t)(jt * 2) * 64 + ln];
    uint4 c1 = Kp[(size_t)(jt * 2 + 1) * 64 + ln];
    for (; jt < 64; jt += 8) {
      const int jn = (jt + 8 < 64) ? jt + 8 : jt;
      const uint4 n0 = Kp[(size_t)(jn * 2) * 64 + ln];
      const uint4 n1 = Kp[(size_t)(jn * 2 + 1) * 64 + ln];
      U4H8 kb0, kb1; kb0.u = c0; kb1.u = c1;
      floatx4 acc = {0.f, 0.f, 0.f, 0.f};
      acc = __builtin_amdgcn_mfma_f32_16x16x32_f16(qa0.h, kb0.h, acc, 0, 0, 0);
      acc = __builtin_amdgcn_mfma_f32_16x16x32_f16(qa1.h, kb1.h, acc, 0, 0, 0);
      const int col = jt * 16 + colL;
#pragma unroll
      for (int r = 0; r < 4; ++r) {
        const float S  = acc[r] * 0.125f;
        const float Sm = (col <= rowD[r]) ? S : NEG_BIG;
        const float tm = rmax16(Sm);
        const bool upd = tm > -1e38f;
        const float mN = upd ? fmaxf(mReg[r], tm) : mReg[r];
        const float ev = __expf(Sm - mN);
        const float ts = radd16(ev);
        const float f  = __expf(mReg[r] - mN);
        sReg[r] = sReg[r] * f + (upd ? ts : 0.f);
        mReg[r] = mN;
      }
      c0 = n0; c1 = n1;
    }
  }
  if ((ln & 15) == 0) {
#pragma unroll
    for (int r = 0; r < 4; ++r) {
      const int m = (ln >> 4) * 4 + r;
      redM[m][wv] = mReg[r];
      redS[m][wv] = sReg[r];
    }
  }
  __syncthreads();

  // ---- combine stats across the 8 waves ----
  float Mrow[4], rsRow[4];
#pragma unroll
  for (int r = 0; r < 4; ++r) {
    const int m = (ln >> 4) * 4 + r;
    float M = redM[m][0];
#pragma unroll
    for (int w = 1; w < 8; ++w) M = fmaxf(M, redM[m][w]);
    float S = 0.f;
#pragma unroll
    for (int w = 0; w < 8; ++w) S += redS[m][w] * __expf(redM[m][w] - M);
    Mrow[r]  = M;
    rsRow[r] = 1.25f / S;        // softmax denom + /(1-p) dropout scale
  }

  // ---- pass 2: recompute scores, P = exp(S-M)*rs, threefry, store ----
  {
    int jt = wv;
    uint4 c0 = Kp[(size_t)(jt * 2) * 64 + ln];
    uint4 c1 = Kp[(size_t)(jt * 2 + 1) * 64 + ln];
    for (; jt < 64; jt += 8) {
      const int jn = (jt + 8 < 64) ? jt + 8 : jt;
      const uint4 n0 = Kp[(size_t)(jn * 2) * 64 + ln];
      const uint4 n1 = Kp[(size_t)(jn * 2 + 1) * 64 + ln];
      U4H8 kb0, kb1; kb0.u = c0; kb1.u = c1;
      floatx4 acc = {0.f, 0.f, 0.f, 0.f};
      acc = __builtin_amdgcn_mfma_f32_16x16x32_f16(qa0.h, kb0.h, acc, 0, 0, 0);
      acc = __builtin_amdgcn_mfma_f32_16x16x32_f16(qa1.h, kb1.h, acc, 0, 0, 0);
      const int col = jt * 16 + colL;
#pragma unroll
      for (int r = 0; r < 4; ++r) {
        float v = 0.f;
        // reg fully masked (max row = g+64*(12+r)) -> skip threefry, store 0
        if (g + 64 * (12 + r) >= jt * 16) {
          const bool valid = (col <= rowD[r]);
          const float S = acc[r] * 0.125f;
          const float e = valid ? __expf(S - Mrow[r]) * rsRow[r] : 0.f;
          v = keep_at(obase[r] + (uint32_t)col) ? e : 0.f;
        }
        O[obase[r] + (uint32_t)col] = v;   // zeros clear the poison
      }
      c0 = n0; c1 = n1;
    }
  }
}

extern "C" void kernel_launch(void* const* d_in, const int* in_sizes, int n_in,
                              void* d_out, int out_size, void* d_ws, size_t ws_size,
                              hipStream_t stream) {
  const float* q = (const float*)d_in[0];
  const float* k = (const float*)d_in[1];
  float* out = (float*)d_out;
  uint32_t* w = (uint32_t*)d_ws;   // 1 MB staging
  cvt_kernel<<<dim3(128), 256, 0, stream>>>(q, k, w);
  attn_kernel<<<dim3(256), 512, 0, stream>>>(w, out);
}

// Round 12
// 29.468 us; speedup vs baseline: 3.8402x; 1.0709x over previous
//
#include <hip/hip_runtime.h>
#include <stdint.h>

// B=4, T=1024, D=64 causal attention probs + deterministic JAX dropout.
// Split-K MFMA version. cvt packs Q (row-major f16) + K (B-frag-major f16).
// stats: 2048 blocks x 256 thr; block (rt,c) = row-tile rt (16 interleaved
// rows g+64m), col-chunk c (8 of 64 jt tiles, 2 per wave); online (m,s) via
// 16-lane DPP; per-chunk partials -> d_ws. final: same decomposition;
// combines 8 partials/row, re-mfmas its chunk, P=exp(S-M)*rs, threefry, store.
#define TT 1024
#define BB 4
#define NEG_BIG (-3.4e38f)
#define QH_U32 (BB * TT * 32)          // 131072 u32 = Q as half2; K follows
#define PART_OFF (2 * QH_U32)          // u32 offset of partial (m,s) array

typedef __fp16 fp16x2 __attribute__((ext_vector_type(2)));
typedef __fp16 fp16x8 __attribute__((ext_vector_type(8)));
typedef float  floatx4 __attribute__((ext_vector_type(4)));
union U32H2 { uint32_t u; fp16x2 h; };
union U4H8  { uint4 u; fp16x8 h; };

__device__ __forceinline__ uint32_t rotl32(uint32_t x, int d) {
  return (x << d) | (x >> (32 - d));
}

// JAX partitionable threefry (key(42)) keep decision  [verified R1]
__device__ __forceinline__ bool keep_at(uint32_t i) {
  uint32_t x0 = 0u, x1 = i;
  const uint32_t ks0 = 0u, ks1 = 42u;
  const uint32_t ks2 = 0x1BD11BDAu ^ ks0 ^ ks1;
  x0 += ks0; x1 += ks1;
#define R4(a,b,c,d)                              \
  x0 += x1; x1 = rotl32(x1,(a)); x1 ^= x0;       \
  x0 += x1; x1 = rotl32(x1,(b)); x1 ^= x0;       \
  x0 += x1; x1 = rotl32(x1,(c)); x1 ^= x0;       \
  x0 += x1; x1 = rotl32(x1,(d)); x1 ^= x0;
  R4(13,15,26,6)   x0 += ks1; x1 += ks2 + 1u;
  R4(17,29,16,24)  x0 += ks2; x1 += ks0 + 2u;
  R4(13,15,26,6)   x0 += ks0; x1 += ks1 + 3u;
  R4(17,29,16,24)  x0 += ks1; x1 += ks2 + 4u;
  R4(13,15,26,6)   x0 += ks2; x1 += ks0 + 5u;
#undef R4
  const uint32_t bits = x0 ^ x1;
  const float u = __uint_as_float((bits >> 9) | 0x3f800000u) - 1.0f;
  return u < 0.8f;
}

__device__ __forceinline__ uint32_t pack2(float x, float y) {
  U32H2 t; t.h = __builtin_amdgcn_cvt_pkrtz(x, y);
  return t.u;
}

template <int CTRL>
__device__ __forceinline__ float maxdpp(float x) {
  const int s =
      __builtin_amdgcn_update_dpp(0, __float_as_int(x), CTRL, 0xF, 0xF, true);
  return fmaxf(x, __int_as_float(s));
}
template <int CTRL>
__device__ __forceinline__ float adddpp(float x) {
  const int s =
      __builtin_amdgcn_update_dpp(0, __float_as_int(x), CTRL, 0xF, 0xF, true);
  return x + __int_as_float(s);
}
__device__ __forceinline__ float rmax16(float a) {
  a = maxdpp<0xB1>(a);  a = maxdpp<0x4E>(a);
  a = maxdpp<0x141>(a); a = maxdpp<0x140>(a);
  return a;
}
__device__ __forceinline__ float radd16(float a) {
  a = adddpp<0xB1>(a);  a = adddpp<0x4E>(a);
  a = adddpp<0x141>(a); a = adddpp<0x140>(a);
  return a;
}

// ---- cvt: Q -> row-major f16; K -> B-frag-major f16  [verified R11] ----
__global__ __launch_bounds__(256)
void cvt_kernel(const float* __restrict__ Q, const float* __restrict__ K,
                uint32_t* __restrict__ W) {
  const int t = blockIdx.x * 256 + threadIdx.x;   // 0..32767
  uint4* W4 = reinterpret_cast<uint4*>(W);
  {
    const int row = t >> 3, c8 = t & 7;
    const float4 f0 = reinterpret_cast<const float4*>(Q)[row * 16 + c8 * 2];
    const float4 f1 = reinterpret_cast<const float4*>(Q)[row * 16 + c8 * 2 + 1];
    uint4 d;
    d.x = pack2(f0.x, f0.y); d.y = pack2(f0.z, f0.w);
    d.z = pack2(f1.x, f1.y); d.w = pack2(f1.z, f1.w);
    W4[t] = d;
  }
  {
    const int l = t & 63, c = (t >> 6) & 1, jt = (t >> 7) & 63, b = t >> 13;
    const int jrow = jt * 16 + (l & 15);
    const int kof  = c * 32 + (l >> 4) * 8;
    const float4 f0 =
        reinterpret_cast<const float4*>(K)[((b << 10) + jrow) * 16 + (kof >> 2)];
    const float4 f1 =
        reinterpret_cast<const float4*>(K)[((b << 10) + jrow) * 16 + (kof >> 2) + 1];
    uint4 d;
    d.x = pack2(f0.x, f0.y); d.y = pack2(f0.z, f0.w);
    d.z = pack2(f1.x, f1.y); d.w = pack2(f1.z, f1.w);
    W4[32768 + t] = d;
  }
}

// ---- stats: per (row-tile, chunk) online (m,s) partials ----
__global__ __launch_bounds__(256)
void stats_kernel(const uint32_t* __restrict__ W, float* __restrict__ P) {
  __shared__ float redM[16][4], redS[16][4];

  const int tid = threadIdx.x;
  const int wv  = tid >> 6, ln = tid & 63;
  const int rt  = blockIdx.x >> 3;      // 0..255
  const int c   = blockIdx.x & 7;       // jt chunk
  const int g   = rt & 63;
  const int b   = rt >> 6;

  const uint4* W4 = reinterpret_cast<const uint4*>(W);
  const uint4* Kp = W4 + 32768 + (size_t)b * 8192;

  const int arow = g + 64 * (ln & 15);
  U4H8 qa0, qa1;
  qa0.u = W4[((size_t)(b << 10) + arow) * 8 + (ln >> 4)];
  qa1.u = W4[((size_t)(b << 10) + arow) * 8 + 4 + (ln >> 4)];

  int rowD[4];
#pragma unroll
  for (int r = 0; r < 4; ++r) rowD[r] = g + 64 * ((ln >> 4) * 4 + r);
  const int colL = ln & 15;

  float mReg[4] = {NEG_BIG, NEG_BIG, NEG_BIG, NEG_BIG};
  float sReg[4] = {0.f, 0.f, 0.f, 0.f};
#pragma unroll
  for (int u = 0; u < 2; ++u) {
    const int jt = c * 8 + wv * 2 + u;
    U4H8 kb0, kb1;
    kb0.u = Kp[(size_t)(jt * 2) * 64 + ln];
    kb1.u = Kp[(size_t)(jt * 2 + 1) * 64 + ln];
    floatx4 acc = {0.f, 0.f, 0.f, 0.f};
    acc = __builtin_amdgcn_mfma_f32_16x16x32_f16(qa0.h, kb0.h, acc, 0, 0, 0);
    acc = __builtin_amdgcn_mfma_f32_16x16x32_f16(qa1.h, kb1.h, acc, 0, 0, 0);
    const int col = jt * 16 + colL;
#pragma unroll
    for (int r = 0; r < 4; ++r) {
      const float S  = acc[r] * 0.125f;
      const float Sm = (col <= rowD[r]) ? S : NEG_BIG;
      const float tm = rmax16(Sm);
      const bool upd = tm > -1e38f;
      const float mN = upd ? fmaxf(mReg[r], tm) : mReg[r];
      const float ev = __expf(Sm - mN);
      const float ts = radd16(ev);
      const float f  = __expf(mReg[r] - mN);
      sReg[r] = sReg[r] * f + (upd ? ts : 0.f);
      mReg[r] = mN;
    }
  }
  if ((ln & 15) == 0) {
#pragma unroll
    for (int r = 0; r < 4; ++r) {
      const int m = (ln >> 4) * 4 + r;
      redM[m][wv] = mReg[r];
      redS[m][wv] = sReg[r];
    }
  }
  __syncthreads();
  // wave 0, lanes 0..15: combine 4 waves, write per-chunk partial
  if (wv == 0 && ln < 16) {
    const int m = ln;
    float M = redM[m][0];
#pragma unroll
    for (int w = 1; w < 4; ++w) M = fmaxf(M, redM[m][w]);
    float S = 0.f;
#pragma unroll
    for (int w = 0; w < 4; ++w) S += redS[m][w] * __expf(redM[m][w] - M);
    float2 out; out.x = M; out.y = S;
    reinterpret_cast<float2*>(P)[((size_t)rt * 8 + c) * 16 + m] = out;
  }
}

// ---- final: combine partials, re-mfma chunk, P=exp(S-M)*rs, threefry ----
__global__ __launch_bounds__(256)
void final_kernel(const uint32_t* __restrict__ W, const float* __restrict__ P,
                  float* __restrict__ O) {
  __shared__ float Ms[16], Rs[16];

  const int tid = threadIdx.x;
  const int wv  = tid >> 6, ln = tid & 63;
  const int rt  = blockIdx.x >> 3;
  const int c   = blockIdx.x & 7;
  const int g   = rt & 63;
  const int b   = rt >> 6;

  // wave 0, lanes 0..15: combine the 8 chunk partials for each row
  if (wv == 0 && ln < 16) {
    const int m = ln;
    const float2* Pp = reinterpret_cast<const float2*>(P) + (size_t)rt * 8 * 16 + m;
    float mc[8], sc[8];
#pragma unroll
    for (int cc = 0; cc < 8; ++cc) {
      const float2 p = Pp[cc * 16];
      mc[cc] = p.x; sc[cc] = p.y;
    }
    float M = mc[0];
#pragma unroll
    for (int cc = 1; cc < 8; ++cc) M = fmaxf(M, mc[cc]);
    float S = 0.f;
#pragma unroll
    for (int cc = 0; cc < 8; ++cc) S += sc[cc] * __expf(mc[cc] - M);
    Ms[m] = M;
    Rs[m] = 1.25f / S;          // softmax denom + /(1-p) dropout scale
  }

  const uint4* W4 = reinterpret_cast<const uint4*>(W);
  const uint4* Kp = W4 + 32768 + (size_t)b * 8192;
  const int arow = g + 64 * (ln & 15);
  U4H8 qa0, qa1;
  qa0.u = W4[((size_t)(b << 10) + arow) * 8 + (ln >> 4)];
  qa1.u = W4[((size_t)(b << 10) + arow) * 8 + 4 + (ln >> 4)];

  int rowD[4]; uint32_t obase[4];
#pragma unroll
  for (int r = 0; r < 4; ++r) {
    const int m = (ln >> 4) * 4 + r;
    rowD[r]  = g + 64 * m;
    obase[r] = ((uint32_t)b << 20) | ((uint32_t)rowD[r] << 10);
  }
  const int colL = ln & 15;

  __syncthreads();
  float Mrow[4], rsRow[4];
#pragma unroll
  for (int r = 0; r < 4; ++r) {
    const int m = (ln >> 4) * 4 + r;
    Mrow[r]  = Ms[m];
    rsRow[r] = Rs[m];
  }

#pragma unroll
  for (int u = 0; u < 2; ++u) {
    const int jt = c * 8 + wv * 2 + u;
    U4H8 kb0, kb1;
    kb0.u = Kp[(size_t)(jt * 2) * 64 + ln];
    kb1.u = Kp[(size_t)(jt * 2 + 1) * 64 + ln];
    floatx4 acc = {0.f, 0.f, 0.f, 0.f};
    acc = __builtin_amdgcn_mfma_f32_16x16x32_f16(qa0.h, kb0.h, acc, 0, 0, 0);
    acc = __builtin_amdgcn_mfma_f32_16x16x32_f16(qa1.h, kb1.h, acc, 0, 0, 0);
    const int col = jt * 16 + colL;
#pragma unroll
    for (int r = 0; r < 4; ++r) {
      float v = 0.f;
      if (g + 64 * (12 + r) >= jt * 16) {   // any lane-group row valid?
        const bool valid = (col <= rowD[r]);
        const float S = acc[r] * 0.125f;
        const float e = valid ? __expf(S - Mrow[r]) * rsRow[r] : 0.f;
        v = keep_at(obase[r] + (uint32_t)col) ? e : 0.f;
      }
      O[obase[r] + (uint32_t)col] = v;      // zeros clear the poison
    }
  }
}

extern "C" void kernel_launch(void* const* d_in, const int* in_sizes, int n_in,
                              void* d_out, int out_size, void* d_ws, size_t ws_size,
                              hipStream_t stream) {
  const float* q = (const float*)d_in[0];
  const float* k = (const float*)d_in[1];
  float* out = (float*)d_out;
  uint32_t* w = (uint32_t*)d_ws;                 // 1 MB staging
  float* part = (float*)(w + PART_OFF);          // 256 KB partials
  cvt_kernel<<<dim3(128), 256, 0, stream>>>(q, k, w);
  stats_kernel<<<dim3(2048), 256, 0, stream>>>(w, part);
  final_kernel<<<dim3(2048), 256, 0, stream>>>(w, part, out);
}

// Round 13
// 24.471 us; speedup vs baseline: 4.6245x; 1.2042x over previous
//
#include <hip/hip_runtime.h>
#include <stdint.h>

// B=4, T=1024, D=64 causal attention probs + deterministic JAX dropout.
// SINGLE fused kernel. Since q,k in [0,1): S = q.k/8 in [0,8] -> exp(S) <= 2981,
// so softmax needs NO max subtraction (ratios identical, fp32-safe).
// 256 blocks x 512 thr. Block = 16 interleaved rows {g+64m}. Each wave owns
// 8 jt col-tiles; packs Q/K f16 fragments in-register from fp32 (no cvt pass),
// mfma -> e=exp(S) kept in VGPRs -> row sums via DPP+LDS -> threefry+store.
#define TT 1024
#define BB 4

typedef __fp16 fp16x2 __attribute__((ext_vector_type(2)));
typedef __fp16 fp16x8 __attribute__((ext_vector_type(8)));
typedef float  floatx4 __attribute__((ext_vector_type(4)));
union U32H2 { uint32_t u; fp16x2 h; };
union U4H8  { uint4 u; fp16x8 h; };

__device__ __forceinline__ uint32_t rotl32(uint32_t x, int d) {
  return (x << d) | (x >> (32 - d));
}

// JAX partitionable threefry (key(42)) keep decision  [verified R1]
__device__ __forceinline__ bool keep_at(uint32_t i) {
  uint32_t x0 = 0u, x1 = i;
  const uint32_t ks0 = 0u, ks1 = 42u;
  const uint32_t ks2 = 0x1BD11BDAu ^ ks0 ^ ks1;
  x0 += ks0; x1 += ks1;
#define R4(a,b,c,d)                              \
  x0 += x1; x1 = rotl32(x1,(a)); x1 ^= x0;       \
  x0 += x1; x1 = rotl32(x1,(b)); x1 ^= x0;       \
  x0 += x1; x1 = rotl32(x1,(c)); x1 ^= x0;       \
  x0 += x1; x1 = rotl32(x1,(d)); x1 ^= x0;
  R4(13,15,26,6)   x0 += ks1; x1 += ks2 + 1u;
  R4(17,29,16,24)  x0 += ks2; x1 += ks0 + 2u;
  R4(13,15,26,6)   x0 += ks0; x1 += ks1 + 3u;
  R4(17,29,16,24)  x0 += ks1; x1 += ks2 + 4u;
  R4(13,15,26,6)   x0 += ks2; x1 += ks0 + 5u;
#undef R4
  const uint32_t bits = x0 ^ x1;
  const float u = __uint_as_float((bits >> 9) | 0x3f800000u) - 1.0f;
  return u < 0.8f;
}

__device__ __forceinline__ uint32_t pack2(float x, float y) {
  U32H2 t; t.h = __builtin_amdgcn_cvt_pkrtz(x, y);
  return t.u;
}
// pack 8 fp32 (two float4) -> fp16x8 fragment
__device__ __forceinline__ U4H8 pack8(float4 f0, float4 f1) {
  U4H8 d;
  d.u.x = pack2(f0.x, f0.y); d.u.y = pack2(f0.z, f0.w);
  d.u.z = pack2(f1.x, f1.y); d.u.w = pack2(f1.z, f1.w);
  return d;
}

template <int CTRL>
__device__ __forceinline__ float adddpp(float x) {
  const int s =
      __builtin_amdgcn_update_dpp(0, __float_as_int(x), CTRL, 0xF, 0xF, true);
  return x + __int_as_float(s);
}
// sum over the 16 lanes of a (l>>4) group  [verified R11/R12]
__device__ __forceinline__ float radd16(float a) {
  a = adddpp<0xB1>(a);  a = adddpp<0x4E>(a);
  a = adddpp<0x141>(a); a = adddpp<0x140>(a);
  return a;
}

__global__ __launch_bounds__(512)
void attn_kernel(const float* __restrict__ Q, const float* __restrict__ K,
                 float* __restrict__ O) {
  __shared__ float redS[16][8];

  const int tid  = threadIdx.x;
  const int wv   = tid >> 6, ln = tid & 63;
  const int colL = ln & 15;          // D col / B-frag col / A,B row selector
  const int kgrp = ln >> 4;          // k-chunk group
  const int g    = blockIdx.x & 63;
  const int b    = blockIdx.x >> 6;

  const float4* Qf = reinterpret_cast<const float4*>(Q) + (size_t)b * TT * 16;
  const float4* Kf = reinterpret_cast<const float4*>(K) + (size_t)b * TT * 16;

  // ---- A-frags (q-tile rows g+64m): lane -> A[row=ln&15][k=kgrp*8+i] ----
  const int arow = g + 64 * (ln & 15);
  const U4H8 qa0 = pack8(Qf[arow * 16 + kgrp * 2],     Qf[arow * 16 + kgrp * 2 + 1]);
  const U4H8 qa1 = pack8(Qf[arow * 16 + 8 + kgrp * 2], Qf[arow * 16 + 8 + kgrp * 2 + 1]);

  // D-side rows per reg r: m = kgrp*4 + r, global row = g + 64m
  int rowD[4]; uint32_t obase[4];
#pragma unroll
  for (int r = 0; r < 4; ++r) {
    rowD[r]  = g + 64 * (kgrp * 4 + r);
    obase[r] = ((uint32_t)b << 20) | ((uint32_t)rowD[r] << 10);
  }

  // ---- pass A: mfma scores, e = exp(S) (no max needed: S in [0,8]) ----
  float p[8][4];                      // e-values, statically indexed
  float sAcc[4] = {0.f, 0.f, 0.f, 0.f};
#pragma unroll
  for (int it = 0; it < 8; ++it) {
    const int jt = it * 8 + wv;
    const int jrow = jt * 16 + colL;  // B-frag source row of K
    // B-frag: lane -> B[k = c*32 + kgrp*8 + i][col = colL], c=0,1
    const U4H8 kb0 = pack8(Kf[jrow * 16 + kgrp * 2],
                           Kf[jrow * 16 + kgrp * 2 + 1]);
    const U4H8 kb1 = pack8(Kf[jrow * 16 + 8 + kgrp * 2],
                           Kf[jrow * 16 + 8 + kgrp * 2 + 1]);
    floatx4 acc = {0.f, 0.f, 0.f, 0.f};
    acc = __builtin_amdgcn_mfma_f32_16x16x32_f16(qa0.h, kb0.h, acc, 0, 0, 0);
    acc = __builtin_amdgcn_mfma_f32_16x16x32_f16(qa1.h, kb1.h, acc, 0, 0, 0);
    const int col = jt * 16 + colL;
#pragma unroll
    for (int r = 0; r < 4; ++r) {
      const float e = (col <= rowD[r]) ? __expf(acc[r] * 0.125f) : 0.f;
      p[it][r] = e;
      sAcc[r] += e;
    }
  }
  // 16-lane sums -> LDS -> combine 8 waves
#pragma unroll
  for (int r = 0; r < 4; ++r) sAcc[r] = radd16(sAcc[r]);
  if (colL == 0) {
#pragma unroll
    for (int r = 0; r < 4; ++r) redS[kgrp * 4 + r][wv] = sAcc[r];
  }
  __syncthreads();
  float rs[4];
#pragma unroll
  for (int r = 0; r < 4; ++r) {
    const int m = kgrp * 4 + r;
    float S = 0.f;
#pragma unroll
    for (int w = 0; w < 8; ++w) S += redS[m][w];
    rs[r] = 1.25f / S;               // softmax denom + /(1-p) dropout scale
  }

  // ---- epilogue: P*rs with deterministic dropout, store everything ----
#pragma unroll
  for (int it = 0; it < 8; ++it) {
    const int jt = it * 8 + wv;
#pragma unroll
    for (int r = 0; r < 4; ++r) {
      const int col = jt * 16 + colL;
      float v = 0.f;
      // tile fully masked iff max row (g+64*(12+r)) < jt*16 -> skip threefry
      if (g + 64 * (12 + r) >= jt * 16) {
        const float e = (col <= rowD[r]) ? p[it][r] * rs[r] : 0.f;
        v = keep_at(obase[r] + (uint32_t)col) ? e : 0.f;
      }
      O[obase[r] + (uint32_t)col] = v;   // zeros clear the poison
    }
  }
}

extern "C" void kernel_launch(void* const* d_in, const int* in_sizes, int n_in,
                              void* d_out, int out_size, void* d_ws, size_t ws_size,
                              hipStream_t stream) {
  const float* q = (const float*)d_in[0];
  const float* k = (const float*)d_in[1];
  float* out = (float*)d_out;
  attn_kernel<<<dim3(BB * 64), 512, 0, stream>>>(q, k, out);
}